// Round 16
// baseline (109.745 us; speedup 1.0000x reference)
//
#include <hip/hip_runtime.h>
#include <hip/hip_bf16.h>

// Problem constants
constexpr int B  = 4;
constexpr int E  = 1024;
constexpr int Wn = 2048;
constexpr int H  = 16;
constexpr int Dh = 64;   // E / H

typedef short bf16x8 __attribute__((ext_vector_type(8)));
typedef float f32x4  __attribute__((ext_vector_type(4)));

__device__ inline unsigned short f2bf(float f){
    unsigned int u = __builtin_bit_cast(unsigned int, f);
    u = (u + 0x7fffu + ((u >> 16) & 1u)) >> 16;   // RNE
    return (unsigned short)u;
}
__device__ inline float bf2f(unsigned short u){
    return __builtin_bit_cast(float, (unsigned int)u << 16);
}
__device__ inline unsigned int pack_bf16_trunc(float lo, float hi){
    return __builtin_amdgcn_perm(__builtin_bit_cast(unsigned int, hi),
                                 __builtin_bit_cast(unsigned int, lo), 0x07060302u);
}
__device__ inline float exp2_fast(float x){ return __builtin_amdgcn_exp2f(x); }
// LDS column swizzle for the prep tile
__device__ inline int SW(int c){ return c ^ (((c >> 5) & 7) << 2); }

// global -> LDS direct DMA, 16B per lane
#define GLDS(g, l) __builtin_amdgcn_global_load_lds( \
    (const __attribute__((address_space(1))) void*)(g), \
    (__attribute__((address_space(3))) void*)(l), 16, 0, 0)

// 19 work items per head (256-query superblocks sb2=0..7, kv chunks of <=8
// stages, near-uniform, heavy-first). SLOTT=-1 -> direct tws write.
__device__ __constant__ signed char SB2T[19] =
    {2,1,3,3,5,5,5,7,7,7,7,4,4,6,6,6,6,4,0};
__device__ __constant__ signed char KV64T[19] =
    {0,0,0,8,0,8,16,0,8,16,24,0,7,0,7,14,21,14,0};
__device__ __constant__ signed char NSTT[19] =
    {12,8,8,8,8,8,8,8,8,8,8,7,7,7,7,7,7,6,4};
__device__ __constant__ signed char SLOTT[19] =
    {-1,-1,0,1,5,6,7,12,13,14,15,2,3,8,9,10,11,4,-1};
__device__ __constant__ signed char LASTT[19] =
    {1,1,0,1,0,0,1,0,0,0,1,0,0,0,0,0,1,1,1};
// k_reduce tables for sb2=3..7
__device__ __constant__ signed char NCHT[5]   = {2,3,3,4,4};
__device__ __constant__ signed char SBASET[5] = {0,2,5,8,12};

// ---------------------------------------------------------------------------
// K_prep: x read once -> xS (shared scaled Q/K operand) + xdi (V, permuted)
// ---------------------------------------------------------------------------
__global__ __launch_bounds__(256) void k_prep(const float* __restrict__ x,
                                              unsigned short* __restrict__ xS,
                                              unsigned short* __restrict__ xdi){
    __shared__ float tile[64*257];
    const float cs = 0.2123304349f;   // sqrt(log2(e)/32)
    const int t  = threadIdx.x;
    const int bh = blockIdx.x >> 3;
    const int w0 = (blockIdx.x & 7) << 8;

    {
        const int r = t >> 2, seg = t & 3;
        const float* src = x + ((size_t)bh*64 + r)*Wn + w0 + seg*64;
        float* dst = tile + r*257;
        #pragma unroll
        for (int i = 0; i < 16; ++i){
            float4 v = *reinterpret_cast<const float4*>(src + i*4);
            int c0 = seg*64 + i*4;
            dst[SW(c0+0)] = v.x; dst[SW(c0+1)] = v.y;
            dst[SW(c0+2)] = v.z; dst[SW(c0+3)] = v.w;
        }
    }
    __syncthreads();

    {
        const int kgw = t & 3, g = (t >> 2) & 7, r0 = t >> 5;
        #pragma unroll
        for (int rr = 0; rr < 8; ++rr){
            const int r = r0*8 + rr;
            const float* base = tile + r*257;
            const int c0 = g*32 + 4*kgw;
            union { unsigned short us[8]; uint4 v; } u;
            #pragma unroll
            for (int j2 = 0; j2 < 4; ++j2){
                u.us[j2]   = f2bf(base[SW(c0 + j2)]);
                u.us[4+j2] = f2bf(base[SW(c0 + 16 + j2)]);
            }
            *reinterpret_cast<uint4*>(xdi + ((size_t)bh*64 + r)*Wn + w0 + g*32 + 8*kgw) = u.v;
        }
    }
    {
        const int w = t;
        #pragma unroll
        for (int dg = 0; dg < 8; ++dg){
            union { unsigned short us[8]; uint4 v; } u;
            #pragma unroll
            for (int i = 0; i < 8; ++i)
                u.us[i] = f2bf(tile[(dg*8 + i)*257 + SW(w)] * cs);
            *reinterpret_cast<uint4*>(xS + ((size_t)bh*Wn + w0 + w)*64 + dg*8) = u.v;
        }
    }
}

// ---------------------------------------------------------------------------
// K2: M_d -> MT (bf16 transposed)
// ---------------------------------------------------------------------------
__global__ void k_MT(const float* __restrict__ M, unsigned short* __restrict__ MT){
    int tid = blockIdx.x*256 + threadIdx.x;
    int f  = tid & (E-1);
    int eg = tid >> 10;
    union { unsigned short us[8]; uint4 v; } u;
    #pragma unroll
    for (int i = 0; i < 8; i++) u.us[i] = f2bf(M[(size_t)(eg*8+i)*E + f]);
    *reinterpret_cast<uint4*>(MT + (size_t)f*E + eg*8) = u.v;
}

// ---------------------------------------------------------------------------
// K3: flash attention, 8-WAVE blocks (512 thr) sharing one 32KB K/V double
// buffer: 256 queries/block, staging cost per wave halves, waves-per-LDS-byte
// doubles. Per 64-key stage: 1 K-GLDS + 1 V-GLDS per wave, vmcnt(2) pipeline.
// Work items from tables; single-chunk items write tws directly, multi-chunk
// items write additive (acc,l) partials (pacc lives in d_out, 32MB exact).
// ---------------------------------------------------------------------------
__global__ __launch_bounds__(512)
void k_attn(const unsigned short* __restrict__ xS,
            const unsigned short* __restrict__ xdi,
            unsigned short* __restrict__ tws,
            unsigned short* __restrict__ pacc,
            float* __restrict__ pl){
    __shared__ char Klds[2*8192];
    __shared__ char Vlds[2*8192];

    const int lane = threadIdx.x & 63;
    const int wv   = threadIdx.x >> 6;          // 0..7
    const int jl = lane & 15, kg = lane >> 4;
    const int sw = jl & 7;

    const int p    = blockIdx.x;
    const int xcd  = p & 7;
    const int hh   = (p >> 3) & 7;
    const int widx = p >> 6;                    // 0..18, heavy first
    const int bh   = xcd*8 + hh;                // heads pinned per XCD

    const int sb2  = SB2T[widx];
    const int kvb  = (int)KV64T[widx] * 64;
    const int nst  = NSTT[widx];
    const int slot = SLOTT[widx];
    const bool isLast = LASTT[widx] != 0;

    const int q0w = sb2*256 + wv*32;            // this wave's query base

    const bf16x8* xSr = reinterpret_cast<const bf16x8*>(xS + (size_t)bh*Wn*Dh);
    bf16x8 bq[2][2];
    #pragma unroll
    for (int jt = 0; jt < 2; jt++){
        bq[jt][0] = xSr[(q0w + jt*16 + jl)*8 + kg];
        bq[jt][1] = xSr[(q0w + jt*16 + jl)*8 + 4 + kg];
    }
    union { bf16x8 v; unsigned short us[8]; } ones;
    #pragma unroll
    for (int i2 = 0; i2 < 8; i2++) ones.us[i2] = 0x3F80;

    f32x4 acc[2][4] = {};
    f32x4 accl[2] = {};

    const char* Kg = (const char*)xS  + (size_t)bh*Wn*128;      // key rows, 128B
    const char* Vg = (const char*)xdi + (size_t)bh*Dh*(Wn*2);   // d rows, 4KB
    const int rloc = 8*wv + (lane >> 3);           // 0..63 (8 waves)
    const int ksw  = ((lane & 7) ^ (rloc & 7))*16; // pre-swizzled src col

    auto STAGE = [&](int buf, int kvT){
        const char* kg0 = Kg + (size_t)(kvT + rloc)*128 + ksw;
        const char* vg0 = Vg + (size_t)rloc*(Wn*2) + kvT*2 + ksw;
        GLDS(kg0, Klds + buf*8192 + wv*1024);
        GLDS(vg0, Vlds + buf*8192 + wv*1024);
    };

    auto computeS = [&](int buf, int s, bool dg){
        const char* Kb = Klds + buf*8192;
        const char* Vb = Vlds + buf*8192;
        const int r0 = s*32 + jl, r1 = r0 + 16;
        bf16x8 k0a = *(const bf16x8*)(Kb + r0*128 + ((kg    )^sw)*16);
        bf16x8 k0b = *(const bf16x8*)(Kb + r0*128 + ((kg + 4)^sw)*16);
        bf16x8 k1a = *(const bf16x8*)(Kb + r1*128 + ((kg    )^sw)*16);
        bf16x8 k1b = *(const bf16x8*)(Kb + r1*128 + ((kg + 4)^sw)*16);
        const int vsw = ((s*4 + kg)^sw)*16;
        bf16x8 v0 = *(const bf16x8*)(Vb + (     jl)*128 + vsw);
        bf16x8 v1 = *(const bf16x8*)(Vb + (16 + jl)*128 + vsw);
        bf16x8 v2 = *(const bf16x8*)(Vb + (32 + jl)*128 + vsw);
        bf16x8 v3 = *(const bf16x8*)(Vb + (48 + jl)*128 + vsw);

        #pragma unroll
        for (int jt = 0; jt < 2; jt++){
            f32x4 s0 = {0,0,0,0}, s1 = {0,0,0,0};
            s0 = __builtin_amdgcn_mfma_f32_16x16x32_bf16(k0a, bq[jt][0], s0, 0,0,0);
            s0 = __builtin_amdgcn_mfma_f32_16x16x32_bf16(k0b, bq[jt][1], s0, 0,0,0);
            s1 = __builtin_amdgcn_mfma_f32_16x16x32_bf16(k1a, bq[jt][0], s1, 0,0,0);
            s1 = __builtin_amdgcn_mfma_f32_16x16x32_bf16(k1b, bq[jt][1], s1, 0,0,0);

            union { bf16x8 v; unsigned int w[4]; } bp;
            if (!dg){
                bp.w[0] = pack_bf16_trunc(exp2_fast(s0[0]), exp2_fast(s0[1]));
                bp.w[1] = pack_bf16_trunc(exp2_fast(s0[2]), exp2_fast(s0[3]));
                bp.w[2] = pack_bf16_trunc(exp2_fast(s1[0]), exp2_fast(s1[1]));
                bp.w[3] = pack_bf16_trunc(exp2_fast(s1[2]), exp2_fast(s1[3]));
            } else {
                const int lim = 16*jt + jl;
                float pp[8];
                #pragma unroll
                for (int r = 0; r < 4; r++){
                    int c = 4*kg + r;
                    pp[r]   = (c      <= lim) ? exp2_fast(s0[r]) : 0.f;
                    pp[4+r] = (c + 16 <= lim) ? exp2_fast(s1[r]) : 0.f;
                }
                bp.w[0] = pack_bf16_trunc(pp[0], pp[1]);
                bp.w[1] = pack_bf16_trunc(pp[2], pp[3]);
                bp.w[2] = pack_bf16_trunc(pp[4], pp[5]);
                bp.w[3] = pack_bf16_trunc(pp[6], pp[7]);
            }
            accl[jt] = __builtin_amdgcn_mfma_f32_16x16x32_bf16(ones.v, bp.v, accl[jt], 0,0,0);
            acc[jt][0] = __builtin_amdgcn_mfma_f32_16x16x32_bf16(v0, bp.v, acc[jt][0], 0,0,0);
            acc[jt][1] = __builtin_amdgcn_mfma_f32_16x16x32_bf16(v1, bp.v, acc[jt][1], 0,0,0);
            acc[jt][2] = __builtin_amdgcn_mfma_f32_16x16x32_bf16(v2, bp.v, acc[jt][2], 0,0,0);
            acc[jt][3] = __builtin_amdgcn_mfma_f32_16x16x32_bf16(v3, bp.v, acc[jt][3], 0,0,0);
        }
    };

    STAGE(0, kvb);
    for (int t = 0; t < nst; ++t){
        const int kvT = kvb + 64*t;
        if (t + 1 < nst){
            STAGE((t+1)&1, kvT + 64);
            asm volatile("s_waitcnt vmcnt(2)" ::: "memory");
        } else {
            asm volatile("s_waitcnt vmcnt(0)" ::: "memory");
        }
        __builtin_amdgcn_s_barrier();
        __builtin_amdgcn_sched_barrier(0);
        #pragma unroll
        for (int s = 0; s < 2; ++s){
            const int kv = kvT + 32*s;
            if (kv > q0w) continue;
            computeS(t & 1, s, isLast && (kv == q0w));
        }
        asm volatile("s_waitcnt lgkmcnt(0)" ::: "memory");
        __builtin_amdgcn_sched_barrier(0);
        __builtin_amdgcn_s_barrier();
    }

    if (slot < 0){
        // ---- direct epilogue: normalize, write tws
        #pragma unroll
        for (int jt = 0; jt < 2; jt++){
            const float inv = 1.0f / accl[jt][0];
            unsigned short* trow = tws + ((size_t)(bh >> 4)*Wn + q0w + jt*16 + jl)*E + (bh & 15)*Dh;
            #pragma unroll
            for (int dt = 0; dt < 4; dt++){
                union { unsigned short us[4]; ushort4 v; } o;
                #pragma unroll
                for (int r = 0; r < 4; r++) o.us[r] = f2bf(acc[jt][dt][r] * inv);
                *reinterpret_cast<ushort4*>(trow + dt*16 + 4*kg) = o.v;
            }
        }
    } else {
        // ---- partial epilogue: bf16 acc + f32 l
        const int gslot = bh*16 + slot;
        if (kg == 0){
            pl[(size_t)gslot*256 + wv*32 + jl]      = accl[0][0];
            pl[(size_t)gslot*256 + wv*32 + 16 + jl] = accl[1][0];
        }
        unsigned short* pa = pacc + (size_t)gslot*16384;
        #pragma unroll
        for (int jt = 0; jt < 2; jt++){
            #pragma unroll
            for (int dt = 0; dt < 4; dt++){
                union { unsigned short us[4]; ushort4 v; } o;
                #pragma unroll
                for (int r = 0; r < 4; r++) o.us[r] = f2bf(acc[jt][dt][r]);
                *reinterpret_cast<ushort4*>(pa + (wv*32 + jt*16 + jl)*64 + dt*16 + 4*kg) = o.v;
            }
        }
    }
}

// ---------------------------------------------------------------------------
// K3b: combine 2-4 chunk partials per (head, sb2 in 3..7), normalize, write
// tws. Grid 320 = 64 heads x 5 superblocks; 512 threads (q=t>>1, d-half=t&1).
// ---------------------------------------------------------------------------
__global__ __launch_bounds__(512) void k_reduce(const unsigned short* __restrict__ pacc,
                                                const float* __restrict__ pl,
                                                unsigned short* __restrict__ tws){
    const int g   = blockIdx.x;
    const int bh  = g / 5, s5 = g % 5;
    const int sb2 = 3 + s5;
    const int t   = threadIdx.x;
    const int qq  = t >> 1;
    const int db  = (t & 1)*32;
    const int nch   = NCHT[s5];
    const int slot0 = bh*16 + SBASET[s5];

    float l = 0.f;
    float a[32];
    #pragma unroll
    for (int i = 0; i < 32; ++i) a[i] = 0.f;
    for (int c = 0; c < nch; ++c){
        l += pl[(size_t)(slot0 + c)*256 + qq];
        const unsigned short* pa = pacc + (size_t)(slot0 + c)*16384 + qq*64 + db;
        #pragma unroll
        for (int i = 0; i < 4; ++i){
            union { uint4 v; unsigned short us[8]; } r0;
            r0.v = *reinterpret_cast<const uint4*>(pa + i*8);
            #pragma unroll
            for (int j2 = 0; j2 < 8; ++j2) a[i*8 + j2] += bf2f(r0.us[j2]);
        }
    }
    const float inv = 1.0f / l;
    unsigned short* tw = tws + ((size_t)(bh >> 4)*Wn + sb2*256 + qq)*E + (bh & 15)*Dh + db;
    #pragma unroll
    for (int i = 0; i < 4; ++i){
        union { uint4 v; unsigned short us[8]; } o;
        #pragma unroll
        for (int j2 = 0; j2 < 8; ++j2) o.us[j2] = f2bf(a[i*8 + j2] * inv);
        *reinterpret_cast<uint4*>(tw + i*8) = o.v;
    }
}

// ---------------------------------------------------------------------------
// K4: out[b][f][w] = sum_e MT[f][e] * t_ws[b][w][e] + b_d[f]   (r12, LDS-staged)
// ---------------------------------------------------------------------------
__global__ __launch_bounds__(256)
void k_gemm(const unsigned short* __restrict__ MT,
            const unsigned short* __restrict__ tws,
            const float* __restrict__ bd,
            float* __restrict__ out){
    __shared__ char Alds[2*16384];
    __shared__ char Blds[2*16384];

    const int lane = threadIdx.x & 63;
    const int wv   = threadIdx.x >> 6;
    const int jl = lane & 15, kg = lane >> 4;
    const int sw = jl & 7;

    const int p   = blockIdx.x;
    const int blk = (p & 7)*64 + (p >> 3);
    const int b  = blk >> 7;
    const int t2 = blk & 127;
    const int fblk = (t2 >> 4)*128;
    const int wblk = (t2 & 15)*128;
    const int f0 = fblk + (wv >> 1)*64;
    const int w0 = wblk + (wv &  1)*64;

    const char* Ag = (const char*)MT + (size_t)fblk*E*2;
    const char* Bg = (const char*)tws + ((size_t)b*Wn + wblk)*E*2;
    const int rloc = 8*wv + (lane >> 3);
    const int scw  = ((lane & 7) ^ (lane >> 3))*16;

    auto STAGE = [&](int buf, int e0){
        char* Ab = Alds + buf*16384;
        char* Bb = Blds + buf*16384;
        const char* ag = Ag + (size_t)rloc*(E*2) + e0*2 + scw;
        const char* bg = Bg + (size_t)rloc*(E*2) + e0*2 + scw;
        #pragma unroll
        for (int g = 0; g < 4; ++g){
            GLDS(ag + (size_t)g*32*(E*2), Ab + g*4096 + wv*1024);
            GLDS(bg + (size_t)g*32*(E*2), Bb + g*4096 + wv*1024);
        }
    };

    f32x4 acc[4][4] = {};

    auto COMP = [&](int buf){
        const char* Ab = Alds + buf*16384 + ((wv >> 1)*64)*128;
        const char* Bb = Blds + buf*16384 + ((wv &  1)*64)*128;
        #pragma unroll
        for (int h = 0; h < 2; ++h){
            const int cs = ((h*4 + kg) ^ sw)*16;
            bf16x8 am[4], bn[4];
            #pragma unroll
            for (int i = 0; i < 4; i++) am[i] = *(const bf16x8*)(Ab + (i*16 + jl)*128 + cs);
            #pragma unroll
            for (int j = 0; j < 4; j++) bn[j] = *(const bf16x8*)(Bb + (j*16 + jl)*128 + cs);
            #pragma unroll
            for (int i = 0; i < 4; i++)
                #pragma unroll
                for (int j = 0; j < 4; j++)
                    acc[i][j] = __builtin_amdgcn_mfma_f32_16x16x32_bf16(am[i], bn[j], acc[i][j], 0,0,0);
        }
    };

    STAGE(0, 0);
    for (int t = 0; t < 16; ++t){
        if (t < 15){
            STAGE((t+1)&1, (t+1)*64);
            asm volatile("s_waitcnt vmcnt(8)" ::: "memory");
        } else {
            asm volatile("s_waitcnt vmcnt(0)" ::: "memory");
        }
        __builtin_amdgcn_s_barrier();
        __builtin_amdgcn_sched_barrier(0);
        COMP(t & 1);
        asm volatile("s_waitcnt lgkmcnt(0)" ::: "memory");
        __builtin_amdgcn_sched_barrier(0);
        __builtin_amdgcn_s_barrier();
    }

    #pragma unroll
    for (int i = 0; i < 4; i++){
        float bias[4];
        #pragma unroll
        for (int r = 0; r < 4; r++) bias[r] = bd[f0 + i*16 + 4*kg + r];
        #pragma unroll
        for (int j = 0; j < 4; j++){
            #pragma unroll
            for (int r = 0; r < 4; r++){
                out[((size_t)b*E + f0 + i*16 + 4*kg + r)*Wn + w0 + j*16 + jl]
                    = acc[i][j][r] + bias[r];
            }
        }
    }
}

// ---------------------------------------------------------------------------
extern "C" void kernel_launch(void* const* d_in, const int* in_sizes, int n_in,
                              void* d_out, int out_size, void* d_ws, size_t ws_size,
                              hipStream_t stream) {
    const float* x  = (const float*)d_in[0];   // (B,E,W)
    const float* Md = (const float*)d_in[1];   // (E,E)
    const float* bd = (const float*)d_in[2];   // (E,)
    float* out = (float*)d_out;                // (B,E,W)

    char* ws = (char*)d_ws;
    unsigned short* xS   = (unsigned short*)(ws);                    // 16 MB
    unsigned short* xdi  = (unsigned short*)(ws + (16u << 20));      // 16 MB
    unsigned short* MT   = (unsigned short*)(ws + (32u << 20));      //  2 MB
    unsigned short* tws  = (unsigned short*)(ws + (34u << 20));      // 16 MB
    float*          pl   = (float*)(ws + (50u << 20));               //  1 MB
    // pacc lives in d_out (exactly 32MB = 64 heads x 16 slots x 32KB);
    // d_out is dead until k_gemm fully overwrites it afterwards.
    unsigned short* pacc = (unsigned short*)d_out;

    hipLaunchKernelGGL(k_prep,   dim3(512),  dim3(256), 0, stream, x, xS, xdi);
    hipLaunchKernelGGL(k_MT,     dim3(512),  dim3(256), 0, stream, Md, MT);
    hipLaunchKernelGGL(k_attn,   dim3(19*64), dim3(512), 0, stream, xS, xdi, tws, pacc, pl);
    hipLaunchKernelGGL(k_reduce, dim3(320),  dim3(512), 0, stream, pacc, pl, tws);
    hipLaunchKernelGGL(k_gemm,   dim3(B*(E/128)*(Wn/128)), dim3(256), 0, stream, MT, tws, bd, out);
}

// Round 17
// 109.356 us; speedup vs baseline: 1.0036x; 1.0036x over previous
//
#include <hip/hip_runtime.h>
#include <hip/hip_bf16.h>

// Problem constants
constexpr int B  = 4;
constexpr int E  = 1024;
constexpr int Wn = 2048;
constexpr int H  = 16;
constexpr int Dh = 64;   // E / H

typedef short bf16x8 __attribute__((ext_vector_type(8)));
typedef float f32x4  __attribute__((ext_vector_type(4)));

__device__ inline unsigned short f2bf(float f){
    unsigned int u = __builtin_bit_cast(unsigned int, f);
    u = (u + 0x7fffu + ((u >> 16) & 1u)) >> 16;   // RNE
    return (unsigned short)u;
}
__device__ inline float bf2f(unsigned short u){
    return __builtin_bit_cast(float, (unsigned int)u << 16);
}
__device__ inline unsigned int pack_bf16_trunc(float lo, float hi){
    return __builtin_amdgcn_perm(__builtin_bit_cast(unsigned int, hi),
                                 __builtin_bit_cast(unsigned int, lo), 0x07060302u);
}
__device__ inline float exp2_fast(float x){ return __builtin_amdgcn_exp2f(x); }
// LDS column swizzle for the prep tile
__device__ inline int SW(int c){ return c ^ (((c >> 5) & 7) << 2); }

// global -> LDS direct DMA, 16B per lane
#define GLDS(g, l) __builtin_amdgcn_global_load_lds( \
    (const __attribute__((address_space(1))) void*)(g), \
    (__attribute__((address_space(3))) void*)(l), 16, 0, 0)

// 19 work items per head (256-query superblocks sb2=0..7, kv chunks of <=8
// stages, near-uniform, heavy-first). SLOTT=-1 -> direct tws write.
__device__ __constant__ signed char SB2T[19] =
    {2,1,3,3,5,5,5,7,7,7,7,4,4,6,6,6,6,4,0};
__device__ __constant__ signed char KV64T[19] =
    {0,0,0,8,0,8,16,0,8,16,24,0,7,0,7,14,21,14,0};
__device__ __constant__ signed char NSTT[19] =
    {12,8,8,8,8,8,8,8,8,8,8,7,7,7,7,7,7,6,4};
__device__ __constant__ signed char SLOTT[19] =
    {-1,-1,0,1,5,6,7,12,13,14,15,2,3,8,9,10,11,4,-1};
__device__ __constant__ signed char LASTT[19] =
    {1,1,0,1,0,0,1,0,0,0,1,0,0,0,0,0,1,1,1};
// k_reduce tables for sb2=3..7
__device__ __constant__ signed char NCHT[5]   = {2,3,3,4,4};
__device__ __constant__ signed char SBASET[5] = {0,2,5,8,12};

// ---------------------------------------------------------------------------
// K_prep: x read once -> xS (shared scaled Q/K operand) + xdi (V, permuted)
// ---------------------------------------------------------------------------
__global__ __launch_bounds__(256) void k_prep(const float* __restrict__ x,
                                              unsigned short* __restrict__ xS,
                                              unsigned short* __restrict__ xdi){
    __shared__ float tile[64*257];
    const float cs = 0.2123304349f;   // sqrt(log2(e)/32)
    const int t  = threadIdx.x;
    const int bh = blockIdx.x >> 3;
    const int w0 = (blockIdx.x & 7) << 8;

    {
        const int r = t >> 2, seg = t & 3;
        const float* src = x + ((size_t)bh*64 + r)*Wn + w0 + seg*64;
        float* dst = tile + r*257;
        #pragma unroll
        for (int i = 0; i < 16; ++i){
            float4 v = *reinterpret_cast<const float4*>(src + i*4);
            int c0 = seg*64 + i*4;
            dst[SW(c0+0)] = v.x; dst[SW(c0+1)] = v.y;
            dst[SW(c0+2)] = v.z; dst[SW(c0+3)] = v.w;
        }
    }
    __syncthreads();

    {
        const int kgw = t & 3, g = (t >> 2) & 7, r0 = t >> 5;
        #pragma unroll
        for (int rr = 0; rr < 8; ++rr){
            const int r = r0*8 + rr;
            const float* base = tile + r*257;
            const int c0 = g*32 + 4*kgw;
            union { unsigned short us[8]; uint4 v; } u;
            #pragma unroll
            for (int j2 = 0; j2 < 4; ++j2){
                u.us[j2]   = f2bf(base[SW(c0 + j2)]);
                u.us[4+j2] = f2bf(base[SW(c0 + 16 + j2)]);
            }
            *reinterpret_cast<uint4*>(xdi + ((size_t)bh*64 + r)*Wn + w0 + g*32 + 8*kgw) = u.v;
        }
    }
    {
        const int w = t;
        #pragma unroll
        for (int dg = 0; dg < 8; ++dg){
            union { unsigned short us[8]; uint4 v; } u;
            #pragma unroll
            for (int i = 0; i < 8; ++i)
                u.us[i] = f2bf(tile[(dg*8 + i)*257 + SW(w)] * cs);
            *reinterpret_cast<uint4*>(xS + ((size_t)bh*Wn + w0 + w)*64 + dg*8) = u.v;
        }
    }
}

// ---------------------------------------------------------------------------
// K2: M_d -> MT (bf16 transposed)
// ---------------------------------------------------------------------------
__global__ void k_MT(const float* __restrict__ M, unsigned short* __restrict__ MT){
    int tid = blockIdx.x*256 + threadIdx.x;
    int f  = tid & (E-1);
    int eg = tid >> 10;
    union { unsigned short us[8]; uint4 v; } u;
    #pragma unroll
    for (int i = 0; i < 8; i++) u.us[i] = f2bf(M[(size_t)(eg*8+i)*E + f]);
    *reinterpret_cast<uint4*>(MT + (size_t)f*E + eg*8) = u.v;
}

// ---------------------------------------------------------------------------
// K3: flash attention, 8-WAVE blocks (512 thr) sharing one 32KB K/V double
// buffer: 256 queries/block, staging cost per wave halves, waves-per-LDS-byte
// doubles. Per 64-key stage: 1 K-GLDS + 1 V-GLDS per wave, vmcnt(2) pipeline.
// Work items from tables; single-chunk items write tws directly, multi-chunk
// items write additive (acc,l) partials (pacc lives in d_out, 32MB exact).
// ---------------------------------------------------------------------------
__global__ __launch_bounds__(512)
void k_attn(const unsigned short* __restrict__ xS,
            const unsigned short* __restrict__ xdi,
            unsigned short* __restrict__ tws,
            unsigned short* __restrict__ pacc,
            float* __restrict__ pl){
    __shared__ char Klds[2*8192];
    __shared__ char Vlds[2*8192];

    const int lane = threadIdx.x & 63;
    const int wv   = threadIdx.x >> 6;          // 0..7
    const int jl = lane & 15, kg = lane >> 4;
    const int sw = jl & 7;

    const int p    = blockIdx.x;
    const int xcd  = p & 7;
    const int hh   = (p >> 3) & 7;
    const int widx = p >> 6;                    // 0..18, heavy first
    const int bh   = xcd*8 + hh;                // heads pinned per XCD

    const int sb2  = SB2T[widx];
    const int kvb  = (int)KV64T[widx] * 64;
    const int nst  = NSTT[widx];
    const int slot = SLOTT[widx];
    const bool isLast = LASTT[widx] != 0;

    const int q0w = sb2*256 + wv*32;            // this wave's query base

    const bf16x8* xSr = reinterpret_cast<const bf16x8*>(xS + (size_t)bh*Wn*Dh);
    bf16x8 bq[2][2];
    #pragma unroll
    for (int jt = 0; jt < 2; jt++){
        bq[jt][0] = xSr[(q0w + jt*16 + jl)*8 + kg];
        bq[jt][1] = xSr[(q0w + jt*16 + jl)*8 + 4 + kg];
    }
    union { bf16x8 v; unsigned short us[8]; } ones;
    #pragma unroll
    for (int i2 = 0; i2 < 8; i2++) ones.us[i2] = 0x3F80;

    f32x4 acc[2][4] = {};
    f32x4 accl[2] = {};

    const char* Kg = (const char*)xS  + (size_t)bh*Wn*128;      // key rows, 128B
    const char* Vg = (const char*)xdi + (size_t)bh*Dh*(Wn*2);   // d rows, 4KB
    const int rloc = 8*wv + (lane >> 3);           // 0..63 (8 waves)
    const int ksw  = ((lane & 7) ^ (rloc & 7))*16; // pre-swizzled src col

    auto STAGE = [&](int buf, int kvT){
        const char* kg0 = Kg + (size_t)(kvT + rloc)*128 + ksw;
        const char* vg0 = Vg + (size_t)rloc*(Wn*2) + kvT*2 + ksw;
        GLDS(kg0, Klds + buf*8192 + wv*1024);
        GLDS(vg0, Vlds + buf*8192 + wv*1024);
    };

    auto computeS = [&](int buf, int s, bool dg){
        const char* Kb = Klds + buf*8192;
        const char* Vb = Vlds + buf*8192;
        const int r0 = s*32 + jl, r1 = r0 + 16;
        bf16x8 k0a = *(const bf16x8*)(Kb + r0*128 + ((kg    )^sw)*16);
        bf16x8 k0b = *(const bf16x8*)(Kb + r0*128 + ((kg + 4)^sw)*16);
        bf16x8 k1a = *(const bf16x8*)(Kb + r1*128 + ((kg    )^sw)*16);
        bf16x8 k1b = *(const bf16x8*)(Kb + r1*128 + ((kg + 4)^sw)*16);
        const int vsw = ((s*4 + kg)^sw)*16;
        bf16x8 v0 = *(const bf16x8*)(Vb + (     jl)*128 + vsw);
        bf16x8 v1 = *(const bf16x8*)(Vb + (16 + jl)*128 + vsw);
        bf16x8 v2 = *(const bf16x8*)(Vb + (32 + jl)*128 + vsw);
        bf16x8 v3 = *(const bf16x8*)(Vb + (48 + jl)*128 + vsw);

        #pragma unroll
        for (int jt = 0; jt < 2; jt++){
            f32x4 s0 = {0,0,0,0}, s1 = {0,0,0,0};
            s0 = __builtin_amdgcn_mfma_f32_16x16x32_bf16(k0a, bq[jt][0], s0, 0,0,0);
            s0 = __builtin_amdgcn_mfma_f32_16x16x32_bf16(k0b, bq[jt][1], s0, 0,0,0);
            s1 = __builtin_amdgcn_mfma_f32_16x16x32_bf16(k1a, bq[jt][0], s1, 0,0,0);
            s1 = __builtin_amdgcn_mfma_f32_16x16x32_bf16(k1b, bq[jt][1], s1, 0,0,0);

            union { bf16x8 v; unsigned int w[4]; } bp;
            if (!dg){
                bp.w[0] = pack_bf16_trunc(exp2_fast(s0[0]), exp2_fast(s0[1]));
                bp.w[1] = pack_bf16_trunc(exp2_fast(s0[2]), exp2_fast(s0[3]));
                bp.w[2] = pack_bf16_trunc(exp2_fast(s1[0]), exp2_fast(s1[1]));
                bp.w[3] = pack_bf16_trunc(exp2_fast(s1[2]), exp2_fast(s1[3]));
            } else {
                const int lim = 16*jt + jl;
                float pp[8];
                #pragma unroll
                for (int r = 0; r < 4; r++){
                    int c = 4*kg + r;
                    pp[r]   = (c      <= lim) ? exp2_fast(s0[r]) : 0.f;
                    pp[4+r] = (c + 16 <= lim) ? exp2_fast(s1[r]) : 0.f;
                }
                bp.w[0] = pack_bf16_trunc(pp[0], pp[1]);
                bp.w[1] = pack_bf16_trunc(pp[2], pp[3]);
                bp.w[2] = pack_bf16_trunc(pp[4], pp[5]);
                bp.w[3] = pack_bf16_trunc(pp[6], pp[7]);
            }
            accl[jt] = __builtin_amdgcn_mfma_f32_16x16x32_bf16(ones.v, bp.v, accl[jt], 0,0,0);
            acc[jt][0] = __builtin_amdgcn_mfma_f32_16x16x32_bf16(v0, bp.v, acc[jt][0], 0,0,0);
            acc[jt][1] = __builtin_amdgcn_mfma_f32_16x16x32_bf16(v1, bp.v, acc[jt][1], 0,0,0);
            acc[jt][2] = __builtin_amdgcn_mfma_f32_16x16x32_bf16(v2, bp.v, acc[jt][2], 0,0,0);
            acc[jt][3] = __builtin_amdgcn_mfma_f32_16x16x32_bf16(v3, bp.v, acc[jt][3], 0,0,0);
        }
    };

    STAGE(0, kvb);
    for (int t = 0; t < nst; ++t){
        const int kvT = kvb + 64*t;
        if (t + 1 < nst){
            STAGE((t+1)&1, kvT + 64);
            asm volatile("s_waitcnt vmcnt(2)" ::: "memory");
        } else {
            asm volatile("s_waitcnt vmcnt(0)" ::: "memory");
        }
        __builtin_amdgcn_s_barrier();
        __builtin_amdgcn_sched_barrier(0);
        #pragma unroll
        for (int s = 0; s < 2; ++s){
            const int kv = kvT + 32*s;
            if (kv > q0w) continue;
            computeS(t & 1, s, isLast && (kv == q0w));
        }
        asm volatile("s_waitcnt lgkmcnt(0)" ::: "memory");
        __builtin_amdgcn_sched_barrier(0);
        __builtin_amdgcn_s_barrier();
    }

    if (slot < 0){
        // ---- direct epilogue: normalize, write tws
        #pragma unroll
        for (int jt = 0; jt < 2; jt++){
            const float inv = 1.0f / accl[jt][0];
            unsigned short* trow = tws + ((size_t)(bh >> 4)*Wn + q0w + jt*16 + jl)*E + (bh & 15)*Dh;
            #pragma unroll
            for (int dt = 0; dt < 4; dt++){
                union { unsigned short us[4]; ushort4 v; } o;
                #pragma unroll
                for (int r = 0; r < 4; r++) o.us[r] = f2bf(acc[jt][dt][r] * inv);
                *reinterpret_cast<ushort4*>(trow + dt*16 + 4*kg) = o.v;
            }
        }
    } else {
        // ---- partial epilogue: bf16 acc + f32 l
        const int gslot = bh*16 + slot;
        if (kg == 0){
            pl[(size_t)gslot*256 + wv*32 + jl]      = accl[0][0];
            pl[(size_t)gslot*256 + wv*32 + 16 + jl] = accl[1][0];
        }
        unsigned short* pa = pacc + (size_t)gslot*16384;
        #pragma unroll
        for (int jt = 0; jt < 2; jt++){
            #pragma unroll
            for (int dt = 0; dt < 4; dt++){
                union { unsigned short us[4]; ushort4 v; } o;
                #pragma unroll
                for (int r = 0; r < 4; r++) o.us[r] = f2bf(acc[jt][dt][r]);
                *reinterpret_cast<ushort4*>(pa + (wv*32 + jt*16 + jl)*64 + dt*16 + 4*kg) = o.v;
            }
        }
    }
}

// ---------------------------------------------------------------------------
// K3b: combine 2-4 chunk partials per (head, sb2 in 3..7), normalize, write
// tws. Grid 320 = 64 heads x 5 superblocks; 512 threads (q=t>>1, d-half=t&1).
// ---------------------------------------------------------------------------
__global__ __launch_bounds__(512) void k_reduce(const unsigned short* __restrict__ pacc,
                                                const float* __restrict__ pl,
                                                unsigned short* __restrict__ tws){
    const int g   = blockIdx.x;
    const int bh  = g / 5, s5 = g % 5;
    const int sb2 = 3 + s5;
    const int t   = threadIdx.x;
    const int qq  = t >> 1;
    const int db  = (t & 1)*32;
    const int nch   = NCHT[s5];
    const int slot0 = bh*16 + SBASET[s5];

    float l = 0.f;
    float a[32];
    #pragma unroll
    for (int i = 0; i < 32; ++i) a[i] = 0.f;
    for (int c = 0; c < nch; ++c){
        l += pl[(size_t)(slot0 + c)*256 + qq];
        const unsigned short* pa = pacc + (size_t)(slot0 + c)*16384 + qq*64 + db;
        #pragma unroll
        for (int i = 0; i < 4; ++i){
            union { uint4 v; unsigned short us[8]; } r0;
            r0.v = *reinterpret_cast<const uint4*>(pa + i*8);
            #pragma unroll
            for (int j2 = 0; j2 < 8; ++j2) a[i*8 + j2] += bf2f(r0.us[j2]);
        }
    }
    const float inv = 1.0f / l;
    unsigned short* tw = tws + ((size_t)(bh >> 4)*Wn + sb2*256 + qq)*E + (bh & 15)*Dh + db;
    #pragma unroll
    for (int i = 0; i < 4; ++i){
        union { uint4 v; unsigned short us[8]; } o;
        #pragma unroll
        for (int j2 = 0; j2 < 8; ++j2) o.us[j2] = f2bf(a[i*8 + j2] * inv);
        *reinterpret_cast<uint4*>(tw + i*8) = o.v;
    }
}

// ---------------------------------------------------------------------------
// K4: out[b][f][w] = sum_e MT[f][e] * t_ws[b][w][e] + b_d[f]   (r12, LDS-staged)
// ---------------------------------------------------------------------------
__global__ __launch_bounds__(256)
void k_gemm(const unsigned short* __restrict__ MT,
            const unsigned short* __restrict__ tws,
            const float* __restrict__ bd,
            float* __restrict__ out){
    __shared__ char Alds[2*16384];
    __shared__ char Blds[2*16384];

    const int lane = threadIdx.x & 63;
    const int wv   = threadIdx.x >> 6;
    const int jl = lane & 15, kg = lane >> 4;
    const int sw = jl & 7;

    const int p   = blockIdx.x;
    const int blk = (p & 7)*64 + (p >> 3);
    const int b  = blk >> 7;
    const int t2 = blk & 127;
    const int fblk = (t2 >> 4)*128;
    const int wblk = (t2 & 15)*128;
    const int f0 = fblk + (wv >> 1)*64;
    const int w0 = wblk + (wv &  1)*64;

    const char* Ag = (const char*)MT + (size_t)fblk*E*2;
    const char* Bg = (const char*)tws + ((size_t)b*Wn + wblk)*E*2;
    const int rloc = 8*wv + (lane >> 3);
    const int scw  = ((lane & 7) ^ (lane >> 3))*16;

    auto STAGE = [&](int buf, int e0){
        char* Ab = Alds + buf*16384;
        char* Bb = Blds + buf*16384;
        const char* ag = Ag + (size_t)rloc*(E*2) + e0*2 + scw;
        const char* bg = Bg + (size_t)rloc*(E*2) + e0*2 + scw;
        #pragma unroll
        for (int g = 0; g < 4; ++g){
            GLDS(ag + (size_t)g*32*(E*2), Ab + g*4096 + wv*1024);
            GLDS(bg + (size_t)g*32*(E*2), Bb + g*4096 + wv*1024);
        }
    };

    f32x4 acc[4][4] = {};

    auto COMP = [&](int buf){
        const char* Ab = Alds + buf*16384 + ((wv >> 1)*64)*128;
        const char* Bb = Blds + buf*16384 + ((wv &  1)*64)*128;
        #pragma unroll
        for (int h = 0; h < 2; ++h){
            const int cs = ((h*4 + kg) ^ sw)*16;
            bf16x8 am[4], bn[4];
            #pragma unroll
            for (int i = 0; i < 4; i++) am[i] = *(const bf16x8*)(Ab + (i*16 + jl)*128 + cs);
            #pragma unroll
            for (int j = 0; j < 4; j++) bn[j] = *(const bf16x8*)(Bb + (j*16 + jl)*128 + cs);
            #pragma unroll
            for (int i = 0; i < 4; i++)
                #pragma unroll
                for (int j = 0; j < 4; j++)
                    acc[i][j] = __builtin_amdgcn_mfma_f32_16x16x32_bf16(am[i], bn[j], acc[i][j], 0,0,0);
        }
    };

    STAGE(0, 0);
    for (int t = 0; t < 16; ++t){
        if (t < 15){
            STAGE((t+1)&1, (t+1)*64);
            asm volatile("s_waitcnt vmcnt(8)" ::: "memory");
        } else {
            asm volatile("s_waitcnt vmcnt(0)" ::: "memory");
        }
        __builtin_amdgcn_s_barrier();
        __builtin_amdgcn_sched_barrier(0);
        COMP(t & 1);
        asm volatile("s_waitcnt lgkmcnt(0)" ::: "memory");
        __builtin_amdgcn_sched_barrier(0);
        __builtin_amdgcn_s_barrier();
    }

    #pragma unroll
    for (int i = 0; i < 4; i++){
        float bias[4];
        #pragma unroll
        for (int r = 0; r < 4; r++) bias[r] = bd[f0 + i*16 + 4*kg + r];
        #pragma unroll
        for (int j = 0; j < 4; j++){
            #pragma unroll
            for (int r = 0; r < 4; r++){
                out[((size_t)b*E + f0 + i*16 + 4*kg + r)*Wn + w0 + j*16 + jl]
                    = acc[i][j][r] + bias[r];
            }
        }
    }
}

// ---------------------------------------------------------------------------
extern "C" void kernel_launch(void* const* d_in, const int* in_sizes, int n_in,
                              void* d_out, int out_size, void* d_ws, size_t ws_size,
                              hipStream_t stream) {
    const float* x  = (const float*)d_in[0];   // (B,E,W)
    const float* Md = (const float*)d_in[1];   // (E,E)
    const float* bd = (const float*)d_in[2];   // (E,)
    float* out = (float*)d_out;                // (B,E,W)

    char* ws = (char*)d_ws;
    unsigned short* xS   = (unsigned short*)(ws);                    // 16 MB
    unsigned short* xdi  = (unsigned short*)(ws + (16u << 20));      // 16 MB
    unsigned short* MT   = (unsigned short*)(ws + (32u << 20));      //  2 MB
    unsigned short* tws  = (unsigned short*)(ws + (34u << 20));      // 16 MB
    float*          pl   = (float*)(ws + (50u << 20));               //  1 MB
    // pacc lives in d_out (exactly 32MB = 64 heads x 16 slots x 32KB);
    // d_out is dead until k_gemm fully overwrites it afterwards.
    unsigned short* pacc = (unsigned short*)d_out;

    hipLaunchKernelGGL(k_prep,   dim3(512),  dim3(256), 0, stream, x, xS, xdi);
    hipLaunchKernelGGL(k_MT,     dim3(512),  dim3(256), 0, stream, Md, MT);
    hipLaunchKernelGGL(k_attn,   dim3(19*64), dim3(512), 0, stream, xS, xdi, tws, pacc, pl);
    hipLaunchKernelGGL(k_reduce, dim3(320),  dim3(512), 0, stream, pacc, pl, tws);
    hipLaunchKernelGGL(k_gemm,   dim3(B*(E/128)*(Wn/128)), dim3(256), 0, stream, MT, tws, bd, out);
}

// Round 18
// 107.523 us; speedup vs baseline: 1.0207x; 1.0170x over previous
//
#include <hip/hip_runtime.h>
#include <hip/hip_bf16.h>

// Problem constants
constexpr int B  = 4;
constexpr int E  = 1024;
constexpr int Wn = 2048;
constexpr int H  = 16;
constexpr int Dh = 64;   // E / H

typedef short bf16x8 __attribute__((ext_vector_type(8)));
typedef float f32x4  __attribute__((ext_vector_type(4)));

__device__ inline unsigned short f2bf(float f){
    unsigned int u = __builtin_bit_cast(unsigned int, f);
    u = (u + 0x7fffu + ((u >> 16) & 1u)) >> 16;   // RNE
    return (unsigned short)u;
}
__device__ inline float bf2f(unsigned short u){
    return __builtin_bit_cast(float, (unsigned int)u << 16);
}
__device__ inline unsigned int pack_bf16_trunc(float lo, float hi){
    return __builtin_amdgcn_perm(__builtin_bit_cast(unsigned int, hi),
                                 __builtin_bit_cast(unsigned int, lo), 0x07060302u);
}
__device__ inline float exp2_fast(float x){ return __builtin_amdgcn_exp2f(x); }
// LDS column swizzle for the prep tile
__device__ inline int SW(int c){ return c ^ (((c >> 5) & 7) << 2); }

// global -> LDS direct DMA, 16B per lane
#define GLDS(g, l) __builtin_amdgcn_global_load_lds( \
    (const __attribute__((address_space(1))) void*)(g), \
    (__attribute__((address_space(3))) void*)(l), 16, 0, 0)

// 19 work items per head (256-query superblocks sb2=0..7, kv chunks of <=8
// stages, near-uniform, heavy-first). SLOTT=-1 -> direct tws write.
__device__ __constant__ signed char SB2T[19] =
    {2,1,3,3,5,5,5,7,7,7,7,4,4,6,6,6,6,4,0};
__device__ __constant__ signed char KV64T[19] =
    {0,0,0,8,0,8,16,0,8,16,24,0,7,0,7,14,21,14,0};
__device__ __constant__ signed char NSTT[19] =
    {12,8,8,8,8,8,8,8,8,8,8,7,7,7,7,7,7,6,4};
__device__ __constant__ signed char SLOTT[19] =
    {-1,-1,0,1,5,6,7,12,13,14,15,2,3,8,9,10,11,4,-1};
__device__ __constant__ signed char LASTT[19] =
    {1,1,0,1,0,0,1,0,0,0,1,0,0,0,0,0,1,1,1};
// k_reduce tables for sb2=3..7
__device__ __constant__ signed char NCHT[5]   = {2,3,3,4,4};
__device__ __constant__ signed char SBASET[5] = {0,2,5,8,12};

// ---------------------------------------------------------------------------
// K_prep: x read once -> xS (shared scaled Q/K operand) + xdi (V, permuted)
// ---------------------------------------------------------------------------
__global__ __launch_bounds__(256) void k_prep(const float* __restrict__ x,
                                              unsigned short* __restrict__ xS,
                                              unsigned short* __restrict__ xdi){
    __shared__ float tile[64*257];
    const float cs = 0.2123304349f;   // sqrt(log2(e)/32)
    const int t  = threadIdx.x;
    const int bh = blockIdx.x >> 3;
    const int w0 = (blockIdx.x & 7) << 8;

    {
        const int r = t >> 2, seg = t & 3;
        const float* src = x + ((size_t)bh*64 + r)*Wn + w0 + seg*64;
        float* dst = tile + r*257;
        #pragma unroll
        for (int i = 0; i < 16; ++i){
            float4 v = *reinterpret_cast<const float4*>(src + i*4);
            int c0 = seg*64 + i*4;
            dst[SW(c0+0)] = v.x; dst[SW(c0+1)] = v.y;
            dst[SW(c0+2)] = v.z; dst[SW(c0+3)] = v.w;
        }
    }
    __syncthreads();

    {
        const int kgw = t & 3, g = (t >> 2) & 7, r0 = t >> 5;
        #pragma unroll
        for (int rr = 0; rr < 8; ++rr){
            const int r = r0*8 + rr;
            const float* base = tile + r*257;
            const int c0 = g*32 + 4*kgw;
            union { unsigned short us[8]; uint4 v; } u;
            #pragma unroll
            for (int j2 = 0; j2 < 4; ++j2){
                u.us[j2]   = f2bf(base[SW(c0 + j2)]);
                u.us[4+j2] = f2bf(base[SW(c0 + 16 + j2)]);
            }
            *reinterpret_cast<uint4*>(xdi + ((size_t)bh*64 + r)*Wn + w0 + g*32 + 8*kgw) = u.v;
        }
    }
    {
        const int w = t;
        #pragma unroll
        for (int dg = 0; dg < 8; ++dg){
            union { unsigned short us[8]; uint4 v; } u;
            #pragma unroll
            for (int i = 0; i < 8; ++i)
                u.us[i] = f2bf(tile[(dg*8 + i)*257 + SW(w)] * cs);
            *reinterpret_cast<uint4*>(xS + ((size_t)bh*Wn + w0 + w)*64 + dg*8) = u.v;
        }
    }
}

// ---------------------------------------------------------------------------
// K2: M_d -> MT (bf16 transposed)
// ---------------------------------------------------------------------------
__global__ void k_MT(const float* __restrict__ M, unsigned short* __restrict__ MT){
    int tid = blockIdx.x*256 + threadIdx.x;
    int f  = tid & (E-1);
    int eg = tid >> 10;
    union { unsigned short us[8]; uint4 v; } u;
    #pragma unroll
    for (int i = 0; i < 8; i++) u.us[i] = f2bf(M[(size_t)(eg*8+i)*E + f]);
    *reinterpret_cast<uint4*>(MT + (size_t)f*E + eg*8) = u.v;
}

// ---------------------------------------------------------------------------
// K3: flash attention, 8-wave blocks, TRIPLE-buffered single-barrier pipeline:
// per 64-key stage exactly ONE s_barrier + ONE counted vmcnt (was 2 barriers
// + lgkmcnt(0) drain). 2-deep prefetch: STAGE(t+2) issued right after the
// barrier writes buf (t+2)%3, mod-3 distinct from the buffers stages t and
// t+1 read; barrier-skew <=1 stage makes the WAR hazard impossible.
// s_setprio(1) around the compute cluster (T5).
// ---------------------------------------------------------------------------
__global__ __launch_bounds__(512)
void k_attn(const unsigned short* __restrict__ xS,
            const unsigned short* __restrict__ xdi,
            unsigned short* __restrict__ tws,
            unsigned short* __restrict__ pacc,
            float* __restrict__ pl){
    __shared__ char Klds[3*8192];
    __shared__ char Vlds[3*8192];

    const int lane = threadIdx.x & 63;
    const int wv   = threadIdx.x >> 6;          // 0..7
    const int jl = lane & 15, kg = lane >> 4;
    const int sw = jl & 7;

    const int p    = blockIdx.x;
    const int xcd  = p & 7;
    const int hh   = (p >> 3) & 7;
    const int widx = p >> 6;                    // 0..18, heavy first
    const int bh   = xcd*8 + hh;                // heads pinned per XCD

    const int sb2  = SB2T[widx];
    const int kvb  = (int)KV64T[widx] * 64;
    const int nst  = NSTT[widx];
    const int slot = SLOTT[widx];
    const bool isLast = LASTT[widx] != 0;

    const int q0w = sb2*256 + wv*32;            // this wave's query base

    const bf16x8* xSr = reinterpret_cast<const bf16x8*>(xS + (size_t)bh*Wn*Dh);
    bf16x8 bq[2][2];
    #pragma unroll
    for (int jt = 0; jt < 2; jt++){
        bq[jt][0] = xSr[(q0w + jt*16 + jl)*8 + kg];
        bq[jt][1] = xSr[(q0w + jt*16 + jl)*8 + 4 + kg];
    }
    union { bf16x8 v; unsigned short us[8]; } ones;
    #pragma unroll
    for (int i2 = 0; i2 < 8; i2++) ones.us[i2] = 0x3F80;

    f32x4 acc[2][4] = {};
    f32x4 accl[2] = {};

    const char* Kg = (const char*)xS  + (size_t)bh*Wn*128;      // key rows, 128B
    const char* Vg = (const char*)xdi + (size_t)bh*Dh*(Wn*2);   // d rows, 4KB
    const int rloc = 8*wv + (lane >> 3);           // 0..63 (8 waves)
    const int ksw  = ((lane & 7) ^ (rloc & 7))*16; // pre-swizzled src col

    auto STAGE = [&](int buf, int kvT){
        const char* kg0 = Kg + (size_t)(kvT + rloc)*128 + ksw;
        const char* vg0 = Vg + (size_t)rloc*(Wn*2) + kvT*2 + ksw;
        GLDS(kg0, Klds + buf*8192 + wv*1024);
        GLDS(vg0, Vlds + buf*8192 + wv*1024);
    };

    auto computeS = [&](int buf, int s, bool dg){
        const char* Kb = Klds + buf*8192;
        const char* Vb = Vlds + buf*8192;
        const int r0 = s*32 + jl, r1 = r0 + 16;
        bf16x8 k0a = *(const bf16x8*)(Kb + r0*128 + ((kg    )^sw)*16);
        bf16x8 k0b = *(const bf16x8*)(Kb + r0*128 + ((kg + 4)^sw)*16);
        bf16x8 k1a = *(const bf16x8*)(Kb + r1*128 + ((kg    )^sw)*16);
        bf16x8 k1b = *(const bf16x8*)(Kb + r1*128 + ((kg + 4)^sw)*16);
        const int vsw = ((s*4 + kg)^sw)*16;
        bf16x8 v0 = *(const bf16x8*)(Vb + (     jl)*128 + vsw);
        bf16x8 v1 = *(const bf16x8*)(Vb + (16 + jl)*128 + vsw);
        bf16x8 v2 = *(const bf16x8*)(Vb + (32 + jl)*128 + vsw);
        bf16x8 v3 = *(const bf16x8*)(Vb + (48 + jl)*128 + vsw);

        #pragma unroll
        for (int jt = 0; jt < 2; jt++){
            f32x4 s0 = {0,0,0,0}, s1 = {0,0,0,0};
            s0 = __builtin_amdgcn_mfma_f32_16x16x32_bf16(k0a, bq[jt][0], s0, 0,0,0);
            s0 = __builtin_amdgcn_mfma_f32_16x16x32_bf16(k0b, bq[jt][1], s0, 0,0,0);
            s1 = __builtin_amdgcn_mfma_f32_16x16x32_bf16(k1a, bq[jt][0], s1, 0,0,0);
            s1 = __builtin_amdgcn_mfma_f32_16x16x32_bf16(k1b, bq[jt][1], s1, 0,0,0);

            union { bf16x8 v; unsigned int w[4]; } bp;
            if (!dg){
                bp.w[0] = pack_bf16_trunc(exp2_fast(s0[0]), exp2_fast(s0[1]));
                bp.w[1] = pack_bf16_trunc(exp2_fast(s0[2]), exp2_fast(s0[3]));
                bp.w[2] = pack_bf16_trunc(exp2_fast(s1[0]), exp2_fast(s1[1]));
                bp.w[3] = pack_bf16_trunc(exp2_fast(s1[2]), exp2_fast(s1[3]));
            } else {
                const int lim = 16*jt + jl;
                float pp[8];
                #pragma unroll
                for (int r = 0; r < 4; r++){
                    int c = 4*kg + r;
                    pp[r]   = (c      <= lim) ? exp2_fast(s0[r]) : 0.f;
                    pp[4+r] = (c + 16 <= lim) ? exp2_fast(s1[r]) : 0.f;
                }
                bp.w[0] = pack_bf16_trunc(pp[0], pp[1]);
                bp.w[1] = pack_bf16_trunc(pp[2], pp[3]);
                bp.w[2] = pack_bf16_trunc(pp[4], pp[5]);
                bp.w[3] = pack_bf16_trunc(pp[6], pp[7]);
            }
            accl[jt] = __builtin_amdgcn_mfma_f32_16x16x32_bf16(ones.v, bp.v, accl[jt], 0,0,0);
            acc[jt][0] = __builtin_amdgcn_mfma_f32_16x16x32_bf16(v0, bp.v, acc[jt][0], 0,0,0);
            acc[jt][1] = __builtin_amdgcn_mfma_f32_16x16x32_bf16(v1, bp.v, acc[jt][1], 0,0,0);
            acc[jt][2] = __builtin_amdgcn_mfma_f32_16x16x32_bf16(v2, bp.v, acc[jt][2], 0,0,0);
            acc[jt][3] = __builtin_amdgcn_mfma_f32_16x16x32_bf16(v3, bp.v, acc[jt][3], 0,0,0);
        }
    };

    // ---- single-barrier triple-buffer pipeline, 2-deep prefetch
    STAGE(0, kvb);
    if (nst > 1) STAGE(1, kvb + 64);
    int cur = 0;
    for (int t = 0; t < nst; ++t){
        const int kvT = kvb + 64*t;
        if (t + 1 < nst){
            asm volatile("s_waitcnt vmcnt(2)" ::: "memory");  // stage t landed
        } else {
            asm volatile("s_waitcnt vmcnt(0)" ::: "memory");
        }
        __builtin_amdgcn_s_barrier();                          // all waves have stage t
        __builtin_amdgcn_sched_barrier(0);
        if (t + 2 < nst){
            const int nb = (cur >= 1) ? cur - 1 : cur + 2;     // (cur+2)%3
            STAGE(nb, kvT + 128);
        }
        __builtin_amdgcn_s_setprio(1);
        #pragma unroll
        for (int s = 0; s < 2; ++s){
            const int kv = kvT + 32*s;
            if (kv > q0w) continue;
            computeS(cur, s, isLast && (kv == q0w));
        }
        __builtin_amdgcn_s_setprio(0);
        cur = (cur == 2) ? 0 : cur + 1;
    }

    if (slot < 0){
        // ---- direct epilogue: normalize, write tws
        #pragma unroll
        for (int jt = 0; jt < 2; jt++){
            const float inv = 1.0f / accl[jt][0];
            unsigned short* trow = tws + ((size_t)(bh >> 4)*Wn + q0w + jt*16 + jl)*E + (bh & 15)*Dh;
            #pragma unroll
            for (int dt = 0; dt < 4; dt++){
                union { unsigned short us[4]; ushort4 v; } o;
                #pragma unroll
                for (int r = 0; r < 4; r++) o.us[r] = f2bf(acc[jt][dt][r] * inv);
                *reinterpret_cast<ushort4*>(trow + dt*16 + 4*kg) = o.v;
            }
        }
    } else {
        // ---- partial epilogue: bf16 acc + f32 l
        const int gslot = bh*16 + slot;
        if (kg == 0){
            pl[(size_t)gslot*256 + wv*32 + jl]      = accl[0][0];
            pl[(size_t)gslot*256 + wv*32 + 16 + jl] = accl[1][0];
        }
        unsigned short* pa = pacc + (size_t)gslot*16384;
        #pragma unroll
        for (int jt = 0; jt < 2; jt++){
            #pragma unroll
            for (int dt = 0; dt < 4; dt++){
                union { unsigned short us[4]; ushort4 v; } o;
                #pragma unroll
                for (int r = 0; r < 4; r++) o.us[r] = f2bf(acc[jt][dt][r]);
                *reinterpret_cast<ushort4*>(pa + (wv*32 + jt*16 + jl)*64 + dt*16 + 4*kg) = o.v;
            }
        }
    }
}

// ---------------------------------------------------------------------------
// K3b: combine 2-4 chunk partials per (head, sb2 in 3..7), normalize, write
// tws. Grid 320 = 64 heads x 5 superblocks; 512 threads (q=t>>1, d-half=t&1).
// ---------------------------------------------------------------------------
__global__ __launch_bounds__(512) void k_reduce(const unsigned short* __restrict__ pacc,
                                                const float* __restrict__ pl,
                                                unsigned short* __restrict__ tws){
    const int g   = blockIdx.x;
    const int bh  = g / 5, s5 = g % 5;
    const int sb2 = 3 + s5;
    const int t   = threadIdx.x;
    const int qq  = t >> 1;
    const int db  = (t & 1)*32;
    const int nch   = NCHT[s5];
    const int slot0 = bh*16 + SBASET[s5];

    float l = 0.f;
    float a[32];
    #pragma unroll
    for (int i = 0; i < 32; ++i) a[i] = 0.f;
    for (int c = 0; c < nch; ++c){
        l += pl[(size_t)(slot0 + c)*256 + qq];
        const unsigned short* pa = pacc + (size_t)(slot0 + c)*16384 + qq*64 + db;
        #pragma unroll
        for (int i = 0; i < 4; ++i){
            union { uint4 v; unsigned short us[8]; } r0;
            r0.v = *reinterpret_cast<const uint4*>(pa + i*8);
            #pragma unroll
            for (int j2 = 0; j2 < 8; ++j2) a[i*8 + j2] += bf2f(r0.us[j2]);
        }
    }
    const float inv = 1.0f / l;
    unsigned short* tw = tws + ((size_t)(bh >> 4)*Wn + sb2*256 + qq)*E + (bh & 15)*Dh + db;
    #pragma unroll
    for (int i = 0; i < 4; ++i){
        union { uint4 v; unsigned short us[8]; } o;
        #pragma unroll
        for (int j2 = 0; j2 < 8; ++j2) o.us[j2] = f2bf(a[i*8 + j2] * inv);
        *reinterpret_cast<uint4*>(tw + i*8) = o.v;
    }
}

// ---------------------------------------------------------------------------
// K4: out[b][f][w] = sum_e MT[f][e] * t_ws[b][w][e] + b_d[f]
// (r12 LDS-staged structure + T5 setprio around the MFMA cluster)
// ---------------------------------------------------------------------------
__global__ __launch_bounds__(256)
void k_gemm(const unsigned short* __restrict__ MT,
            const unsigned short* __restrict__ tws,
            const float* __restrict__ bd,
            float* __restrict__ out){
    __shared__ char Alds[2*16384];
    __shared__ char Blds[2*16384];

    const int lane = threadIdx.x & 63;
    const int wv   = threadIdx.x >> 6;
    const int jl = lane & 15, kg = lane >> 4;
    const int sw = jl & 7;

    const int p   = blockIdx.x;
    const int blk = (p & 7)*64 + (p >> 3);
    const int b  = blk >> 7;
    const int t2 = blk & 127;
    const int fblk = (t2 >> 4)*128;
    const int wblk = (t2 & 15)*128;
    const int f0 = fblk + (wv >> 1)*64;
    const int w0 = wblk + (wv &  1)*64;

    const char* Ag = (const char*)MT + (size_t)fblk*E*2;
    const char* Bg = (const char*)tws + ((size_t)b*Wn + wblk)*E*2;
    const int rloc = 8*wv + (lane >> 3);
    const int scw  = ((lane & 7) ^ (lane >> 3))*16;

    auto STAGE = [&](int buf, int e0){
        char* Ab = Alds + buf*16384;
        char* Bb = Blds + buf*16384;
        const char* ag = Ag + (size_t)rloc*(E*2) + e0*2 + scw;
        const char* bg = Bg + (size_t)rloc*(E*2) + e0*2 + scw;
        #pragma unroll
        for (int g = 0; g < 4; ++g){
            GLDS(ag + (size_t)g*32*(E*2), Ab + g*4096 + wv*1024);
            GLDS(bg + (size_t)g*32*(E*2), Bb + g*4096 + wv*1024);
        }
    };

    f32x4 acc[4][4] = {};

    auto COMP = [&](int buf){
        const char* Ab = Alds + buf*16384 + ((wv >> 1)*64)*128;
        const char* Bb = Blds + buf*16384 + ((wv &  1)*64)*128;
        #pragma unroll
        for (int h = 0; h < 2; ++h){
            const int cs = ((h*4 + kg) ^ sw)*16;
            bf16x8 am[4], bn[4];
            #pragma unroll
            for (int i = 0; i < 4; i++) am[i] = *(const bf16x8*)(Ab + (i*16 + jl)*128 + cs);
            #pragma unroll
            for (int j = 0; j < 4; j++) bn[j] = *(const bf16x8*)(Bb + (j*16 + jl)*128 + cs);
            #pragma unroll
            for (int i = 0; i < 4; i++)
                #pragma unroll
                for (int j = 0; j < 4; j++)
                    acc[i][j] = __builtin_amdgcn_mfma_f32_16x16x32_bf16(am[i], bn[j], acc[i][j], 0,0,0);
        }
    };

    STAGE(0, 0);
    for (int t = 0; t < 16; ++t){
        if (t < 15){
            STAGE((t+1)&1, (t+1)*64);
            asm volatile("s_waitcnt vmcnt(8)" ::: "memory");
        } else {
            asm volatile("s_waitcnt vmcnt(0)" ::: "memory");
        }
        __builtin_amdgcn_s_barrier();
        __builtin_amdgcn_sched_barrier(0);
        __builtin_amdgcn_s_setprio(1);
        COMP(t & 1);
        __builtin_amdgcn_s_setprio(0);
        asm volatile("s_waitcnt lgkmcnt(0)" ::: "memory");
        __builtin_amdgcn_sched_barrier(0);
        __builtin_amdgcn_s_barrier();
    }

    #pragma unroll
    for (int i = 0; i < 4; i++){
        float bias[4];
        #pragma unroll
        for (int r = 0; r < 4; r++) bias[r] = bd[f0 + i*16 + 4*kg + r];
        #pragma unroll
        for (int j = 0; j < 4; j++){
            #pragma unroll
            for (int r = 0; r < 4; r++){
                out[((size_t)b*E + f0 + i*16 + 4*kg + r)*Wn + w0 + j*16 + jl]
                    = acc[i][j][r] + bias[r];
            }
        }
    }
}

// ---------------------------------------------------------------------------
extern "C" void kernel_launch(void* const* d_in, const int* in_sizes, int n_in,
                              void* d_out, int out_size, void* d_ws, size_t ws_size,
                              hipStream_t stream) {
    const float* x  = (const float*)d_in[0];   // (B,E,W)
    const float* Md = (const float*)d_in[1];   // (E,E)
    const float* bd = (const float*)d_in[2];   // (E,)
    float* out = (float*)d_out;                // (B,E,W)

    char* ws = (char*)d_ws;
    unsigned short* xS   = (unsigned short*)(ws);                    // 16 MB
    unsigned short* xdi  = (unsigned short*)(ws + (16u << 20));      // 16 MB
    unsigned short* MT   = (unsigned short*)(ws + (32u << 20));      //  2 MB
    unsigned short* tws  = (unsigned short*)(ws + (34u << 20));      // 16 MB
    float*          pl   = (float*)(ws + (50u << 20));               //  1 MB
    // pacc lives in d_out (32MB exact); dead until k_gemm overwrites it.
    unsigned short* pacc = (unsigned short*)d_out;

    hipLaunchKernelGGL(k_prep,   dim3(512),  dim3(256), 0, stream, x, xS, xdi);
    hipLaunchKernelGGL(k_MT,     dim3(512),  dim3(256), 0, stream, Md, MT);
    hipLaunchKernelGGL(k_attn,   dim3(19*64), dim3(512), 0, stream, xS, xdi, tws, pacc, pl);
    hipLaunchKernelGGL(k_reduce, dim3(320),  dim3(512), 0, stream, pacc, pl, tws);
    hipLaunchKernelGGL(k_gemm,   dim3(B*(E/128)*(Wn/128)), dim3(256), 0, stream, MT, tws, bd, out);
}